// Round 7
// baseline (288.587 us; speedup 1.0000x reference)
//
#include <hip/hip_runtime.h>

#define D 64
#define CAP 64

typedef unsigned short u16;
typedef unsigned int u32;
typedef short bf16x8 __attribute__((ext_vector_type(8)));
typedef float f32x4 __attribute__((ext_vector_type(4)));

__device__ __forceinline__ u16 f2bf(float f) {
    u32 u = __float_as_uint(f);
    return (u16)((u + 0x7FFFu + ((u >> 16) & 1u)) >> 16);   // RNE
}

// ---- X->bf16 convert + cnt zeroing + W-fragment prepack + bias prepack ----
__global__ void k_prep(const float* __restrict__ X, u16* __restrict__ Xbf,
                       int* __restrict__ cnt, int n4, int N,
                       const float* __restrict__ Wrel1, const float* __restrict__ Wroot1,
                       const float* __restrict__ Wrel3, const float* __restrict__ Wroot3,
                       const float* __restrict__ brel1, const float* __restrict__ broot1,
                       const float* __restrict__ brel2, const float* __restrict__ broot2,
                       const float* __restrict__ brel3, const float* __restrict__ broot3,
                       u16* __restrict__ Wpk, float* __restrict__ Bpk) {
    int i = blockIdx.x * blockDim.x + threadIdx.x;
    if (i < N) cnt[i] = 0;

    if (i < 2048) {           // W fragment prepack: 32 frags x 64 lanes
        int f    = i >> 6;    // ((stage*2+mat)*4+t)*2+kk
        int lane = i & 63;
        int stage = f >> 4, rest = f & 15;
        int mat = rest >> 3, t = (rest >> 1) & 3, kk = rest & 1;
        int ml = lane & 15, ql = lane >> 4;
        const float* W = stage ? (mat ? Wroot3 : Wrel3) : (mat ? Wroot1 : Wrel1);
        const float* src = W + (t * 16 + ml) * D + kk * 32 + ql * 8;
        union { u16 h[8]; uint4 v; } o;
#pragma unroll
        for (int e = 0; e < 8; ++e) o.h[e] = f2bf(src[e]);
        *reinterpret_cast<uint4*>(Wpk + (size_t)(f * 64 + lane) * 8) = o.v;
    }
    if (i < 128) {            // bias prepack
        int stage = i >> 6, c = i & 63;
        Bpk[i] = stage ? (brel3[c] + broot3[c])
                       : (brel1[c] + broot1[c] + brel2[c] + broot2[c]);
    }

    if (i >= n4) return;
    float4 v = reinterpret_cast<const float4*>(X)[i];
    ushort4 o;
    o.x = f2bf(v.x); o.y = f2bf(v.y); o.z = f2bf(v.z); o.w = f2bf(v.w);
    reinterpret_cast<ushort4*>(Xbf)[i] = o;
}

// ---- XCD-partitioned bucket fill (R6 version, unchanged) ----
__global__ void k_fill(const int* __restrict__ ei, const float* __restrict__ ew,
                       int* __restrict__ cnt, u32* __restrict__ pairs,
                       int E, int step) {
    const int g  = blockIdx.x & 7;
    const int b  = blockIdx.x >> 3;
    const int lo = g * step;
    const int hi = lo + step;
    const int nthr = (gridDim.x >> 3) * blockDim.x;
    const int t  = b * blockDim.x + threadIdx.x;
    const int nchunk = E >> 2;

    for (int c = t; c < nchunk; c += nthr) {
        int e = c * 4;
        int4 d4 = *reinterpret_cast<const int4*>(ei + E + e);
#define DO_EDGE(dd, kk)                                                          \
        if ((dd) >= lo && (dd) < hi) {                                           \
            int p = atomicAdd(cnt + (dd), 1);                                    \
            if (p < CAP)                                                         \
                pairs[(dd) * CAP + p] =                                          \
                    (((u32)f2bf(ew[e + kk])) << 16) | (u32)ei[e + kk];           \
        }
        DO_EDGE(d4.x, 0)
        DO_EDGE(d4.y, 1)
        DO_EDGE(d4.z, 2)
        DO_EDGE(d4.w, 3)
#undef DO_EDGE
    }
    if (g == 0 && t == 0) {
        for (int e = nchunk * 4; e < E; ++e) {
            int d = ei[E + e];
            int p = atomicAdd(cnt + d, 1);
            if (p < CAP) pairs[d * CAP + p] = (((u32)f2bf(ew[e])) << 16) | (u32)ei[e];
        }
    }
}

// ---- fused stage: 4-node strip, SGPR-addressed pipelined gather + MFMA ----
// Per record target asm: v_readlane (uniform row ptr + SGPR weight) ->
// global_load_ushort saddr-form -> v_lshl + v_fmac(v,s,v). Padded slots have
// pp==0 -> weight 0, row 0 (L1-hot), straight-line code.
template <int STAGE>
__global__ __launch_bounds__(256, 6) void k_stage(
        const u16* __restrict__ Gbf,
        const u16* __restrict__ Wpk,   // 16 frags x 64 lanes x 8 bf16 (this stage)
        const float* __restrict__ Bpk, // 64 floats (this stage)
        const int* __restrict__ cnt, const u32* __restrict__ pairs,
        float* __restrict__ outF, u16* __restrict__ outBf, int N) {
    __shared__ __align__(16) u16 smem[4 * 4 * 72];
    const int lane = threadIdx.x & 63;
    const int wid  = threadIdx.x >> 6;
    const int ml   = lane & 15;
    const int ql   = lane >> 4;
    const int n0   = blockIdx.x * 16 + wid * 4;
    u16* sw = smem + wid * 4 * 72;

    if (n0 >= N) return;   // waves independent, no barriers

    int cidx = n0 + (lane & 3); if (cidx >= N) cidx = N - 1;
    const int cnt4 = cnt[cidx];

    int deg[4], degmax = 0;
#pragma unroll
    for (int i = 0; i < 4; ++i) {
        int d = (n0 + i < N) ? __builtin_amdgcn_readlane(cnt4, i) : 0;
        if (d > CAP) d = CAP;
        deg[i] = d;
        degmax = degmax > d ? degmax : d;
    }

    u32 pp[4];
#pragma unroll
    for (int i = 0; i < 4; ++i) {
        int r = n0 + i; if (r >= N) r = N - 1;
        pp[i] = (lane < deg[i]) ? pairs[(size_t)r * CAP + lane] : 0u;
    }

    float acc[4];
#pragma unroll
    for (int i = 0; i < 4; ++i) acc[i] = 0.f;

    u32 vA[4][4], vB[4][4];
    float wA[4][4], wB[4][4];   // uniform (SGPR) weights carried issue->consume
#define ISSUE(vbuf, wbuf, jj)                                                   \
    _Pragma("unroll") for (int s = 0; s < 4; ++s)                               \
    _Pragma("unroll") for (int i = 0; i < 4; ++i) {                             \
        int su = __builtin_amdgcn_readlane((int)pp[i], (jj) + s);               \
        wbuf[s][i] = __uint_as_float((u32)su & 0xFFFF0000u);                    \
        const u16* rowp = Gbf + (((u32)su & 0xFFFFu) << 6);  /* uniform */      \
        vbuf[s][i] = (u32)rowp[lane];                                           \
    }
#define CONSUME(vbuf, wbuf)                                                     \
    _Pragma("unroll") for (int s = 0; s < 4; ++s)                               \
    _Pragma("unroll") for (int i = 0; i < 4; ++i)                               \
        acc[i] = fmaf(wbuf[s][i], __uint_as_float(vbuf[s][i] << 16), acc[i]);

    if (degmax > 0) {
        int j = 0;
        ISSUE(vA, wA, 0)
        for (;;) {
            if (j + 4 < degmax) ISSUE(vB, wB, j + 4)
            CONSUME(vA, wA)
            j += 4;
            if (j >= degmax) break;
            if (j + 4 < degmax) ISSUE(vA, wA, j + 4)
            CONSUME(vB, wB)
            j += 4;
            if (j >= degmax) break;
        }
    }
#undef ISSUE
#undef CONSUME

#pragma unroll
    for (int i = 0; i < 4; ++i) sw[i * 72 + lane] = f2bf(acc[i]);

    // ---- B fragments: prepacked, 16 x dwordx4 loads ----
    bf16x8 brel[4][2], broot[4][2];
#pragma unroll
    for (int t = 0; t < 4; ++t)
#pragma unroll
        for (int kk = 0; kk < 2; ++kk) {
            brel[t][kk]  = *reinterpret_cast<const bf16x8*>(Wpk + (size_t)(((0 * 4 + t) * 2 + kk) * 64 + lane) * 8);
            broot[t][kk] = *reinterpret_cast<const bf16x8*>(Wpk + (size_t)(((1 * 4 + t) * 2 + kk) * 64 + lane) * 8);
        }

    // ---- A fragments: agg from LDS strip, root from global bf16 ----
    const int am = ml & 3;     // strip has 4 rows; rows 4..15 duplicate (stores masked)
    bf16x8 a_agg[2], a_x[2];
#pragma unroll
    for (int kk = 0; kk < 2; ++kk)
        a_agg[kk] = *reinterpret_cast<bf16x8*>(sw + am * 72 + kk * 32 + ql * 8);
    {
        int r = n0 + am; if (r >= N) r = N - 1;
#pragma unroll
        for (int kk = 0; kk < 2; ++kk)
            a_x[kk] = *reinterpret_cast<const bf16x8*>(Gbf + (size_t)r * D + kk * 32 + ql * 8);
    }

    // ---- MFMA + epilogue ----
#pragma unroll
    for (int t = 0; t < 4; ++t) {
        int c = t * 16 + ml;
        float bias = Bpk[c];

        f32x4 accv = {0.f, 0.f, 0.f, 0.f};
        accv = __builtin_amdgcn_mfma_f32_16x16x32_bf16(a_agg[0], brel[t][0],  accv, 0, 0, 0);
        accv = __builtin_amdgcn_mfma_f32_16x16x32_bf16(a_agg[1], brel[t][1],  accv, 0, 0, 0);
        accv = __builtin_amdgcn_mfma_f32_16x16x32_bf16(a_x[0],   broot[t][0], accv, 0, 0, 0);
        accv = __builtin_amdgcn_mfma_f32_16x16x32_bf16(a_x[1],   broot[t][1], accv, 0, 0, 0);
        if (ql == 0) {                      // strip rows 0..3 only
#pragma unroll
            for (int r = 0; r < 4; ++r) {
                int row = n0 + r;           // C/D: row=(lane>>4)*4+reg, col=lane&15
                if (row < N) {
                    float z = accv[r] + bias;
                    float h = 1.f / (1.f + __expf(-z));
                    int off = row * D + c;
                    if (STAGE == 1) outBf[off] = f2bf(h);
                    else            outF[off]  = h;
                }
            }
        }
    }
}

extern "C" void kernel_launch(void* const* d_in, const int* in_sizes, int n_in,
                              void* d_out, int out_size, void* d_ws, size_t ws_size,
                              hipStream_t stream) {
    const float* X      = (const float*)d_in[0];
    const int*   ei     = (const int*)  d_in[1];
    const float* ew     = (const float*)d_in[2];
    const float* Wrel1  = (const float*)d_in[3];
    const float* brel1  = (const float*)d_in[4];
    const float* Wroot1 = (const float*)d_in[5];
    const float* broot1 = (const float*)d_in[6];
    // d_in[7], d_in[9] (Wrel2, Wroot2) multiply H_prev==0 -> unused
    const float* brel2  = (const float*)d_in[8];
    const float* broot2 = (const float*)d_in[10];
    const float* Wrel3  = (const float*)d_in[11];
    const float* brel3  = (const float*)d_in[12];
    const float* Wroot3 = (const float*)d_in[13];
    const float* broot3 = (const float*)d_in[14];

    const int N = in_sizes[0] / D;
    const int E = in_sizes[1] / 2;

    char* ws = (char*)d_ws;
    int* cnt = (int*)ws;
    size_t off = (((size_t)N * 4) + 255) & ~(size_t)255;
    u32* pairs = (u32*)(ws + off);        off += (size_t)N * CAP * 4;
    u16* Xbf   = (u16*)(ws + off);        off += (size_t)N * D * 2;
    u16* Hbf   = (u16*)(ws + off);        off += (size_t)N * D * 2;
    u16* Wpk   = (u16*)(ws + off);        off += (size_t)32 * 64 * 8 * 2;
    float* Bpk = (float*)(ws + off);

    {
        int n4 = N * D / 4;
        int T  = n4 > N ? n4 : N;
        k_prep<<<(T + 255) / 256, 256, 0, stream>>>(
            X, Xbf, cnt, n4, N, Wrel1, Wroot1, Wrel3, Wroot3,
            brel1, broot1, brel2, broot2, brel3, broot3, Wpk, Bpk);
    }
    {
        int step = (N + 7) / 8;
        k_fill<<<1600, 256, 0, stream>>>(ei, ew, cnt, pairs, E, step);
    }

    const int NB = (N + 15) / 16;
    k_stage<1><<<NB, 256, 0, stream>>>(Xbf, Wpk, Bpk,
                                       cnt, pairs, nullptr, Hbf, N);
    k_stage<2><<<NB, 256, 0, stream>>>(Hbf, Wpk + 16 * 64 * 8, Bpk + 64,
                                       cnt, pairs, (float*)d_out, nullptr, N);
}

// Round 8
// 214.171 us; speedup vs baseline: 1.3475x; 1.3475x over previous
//
#include <hip/hip_runtime.h>

#define D 64
#define CAP 64

typedef unsigned short u16;
typedef unsigned int u32;
typedef short bf16x8 __attribute__((ext_vector_type(8)));
typedef float f32x4 __attribute__((ext_vector_type(4)));

__device__ __forceinline__ u16 f2bf(float f) {
    u32 u = __float_as_uint(f);
    return (u16)((u + 0x7FFFu + ((u >> 16) & 1u)) >> 16);   // RNE
}

// ---- X->bf16 convert + cnt zeroing + W-fragment prepack + bias prepack ----
__global__ void k_prep(const float* __restrict__ X, u16* __restrict__ Xbf,
                       int* __restrict__ cnt, int n4, int N,
                       const float* __restrict__ Wrel1, const float* __restrict__ Wroot1,
                       const float* __restrict__ Wrel3, const float* __restrict__ Wroot3,
                       const float* __restrict__ brel1, const float* __restrict__ broot1,
                       const float* __restrict__ brel2, const float* __restrict__ broot2,
                       const float* __restrict__ brel3, const float* __restrict__ broot3,
                       u16* __restrict__ Wpk, float* __restrict__ Bpk) {
    int i = blockIdx.x * blockDim.x + threadIdx.x;
    if (i < N) cnt[i] = 0;

    if (i < 2048) {           // W fragment prepack: 32 frags x 64 lanes
        int f    = i >> 6;    // ((stage*2+mat)*4+t)*2+kk
        int lane = i & 63;
        int stage = f >> 4, rest = f & 15;
        int mat = rest >> 3, t = (rest >> 1) & 3, kk = rest & 1;
        int ml = lane & 15, ql = lane >> 4;
        const float* W = stage ? (mat ? Wroot3 : Wrel3) : (mat ? Wroot1 : Wrel1);
        const float* src = W + (t * 16 + ml) * D + kk * 32 + ql * 8;
        union { u16 h[8]; uint4 v; } o;
#pragma unroll
        for (int e = 0; e < 8; ++e) o.h[e] = f2bf(src[e]);
        *reinterpret_cast<uint4*>(Wpk + (size_t)(f * 64 + lane) * 8) = o.v;
    }
    if (i < 128) {            // bias prepack
        int stage = i >> 6, c = i & 63;
        Bpk[i] = stage ? (brel3[c] + broot3[c])
                       : (brel1[c] + broot1[c] + brel2[c] + broot2[c]);
    }

    if (i >= n4) return;
    float4 v = reinterpret_cast<const float4*>(X)[i];
    ushort4 o;
    o.x = f2bf(v.x); o.y = f2bf(v.y); o.z = f2bf(v.z); o.w = f2bf(v.w);
    reinterpret_cast<ushort4*>(Xbf)[i] = o;
}

// ---- XCD-partitioned bucket fill (proven R6 version) ----
__global__ void k_fill(const int* __restrict__ ei, const float* __restrict__ ew,
                       int* __restrict__ cnt, u32* __restrict__ pairs,
                       int E, int step) {
    const int g  = blockIdx.x & 7;
    const int b  = blockIdx.x >> 3;
    const int lo = g * step;
    const int hi = lo + step;
    const int nthr = (gridDim.x >> 3) * blockDim.x;
    const int t  = b * blockDim.x + threadIdx.x;
    const int nchunk = E >> 2;

    for (int c = t; c < nchunk; c += nthr) {
        int e = c * 4;
        int4 d4 = *reinterpret_cast<const int4*>(ei + E + e);
#define DO_EDGE(dd, kk)                                                          \
        if ((dd) >= lo && (dd) < hi) {                                           \
            int p = atomicAdd(cnt + (dd), 1);                                    \
            if (p < CAP)                                                         \
                pairs[(dd) * CAP + p] =                                          \
                    (((u32)f2bf(ew[e + kk])) << 16) | (u32)ei[e + kk];           \
        }
        DO_EDGE(d4.x, 0)
        DO_EDGE(d4.y, 1)
        DO_EDGE(d4.z, 2)
        DO_EDGE(d4.w, 3)
#undef DO_EDGE
    }
    if (g == 0 && t == 0) {
        for (int e = nchunk * 4; e < E; ++e) {
            int d = ei[E + e];
            int p = atomicAdd(cnt + d, 1);
            if (p < CAP) pairs[d * CAP + p] = (((u32)f2bf(ew[e])) << 16) | (u32)ei[e];
        }
    }
}

// ---- fused stage: 8-node strip, triple-buffered gather + MFMA + sigmoid ----
// R6 proven structure; launch_bounds (256,3) leaves VGPR headroom (R7 lesson:
// (256,6) caused scratch spill, WRITE_SIZE 33->166 MB). Issue-2-ahead gather.
template <int STAGE>
__global__ __launch_bounds__(256, 3) void k_stage(
        const u16* __restrict__ Gbf,
        const u16* __restrict__ Wpk,   // 16 frags x 64 lanes x 8 bf16 (this stage)
        const float* __restrict__ Bpk, // 64 floats (this stage)
        const int* __restrict__ cnt, const u32* __restrict__ pairs,
        float* __restrict__ outF, u16* __restrict__ outBf, int N) {
    __shared__ __align__(16) u16 smem[4 * 8 * 72];
    const int lane = threadIdx.x & 63;
    const int wid  = threadIdx.x >> 6;
    const int ml   = lane & 15;
    const int ql   = lane >> 4;
    const int n0   = blockIdx.x * 32 + wid * 8;
    u16* sw = smem + wid * 8 * 72;

    if (n0 >= N) return;   // waves independent, no barriers

    int cidx = n0 + (lane & 7); if (cidx >= N) cidx = N - 1;
    const int cnt8 = cnt[cidx];

    int deg[8], degmax = 0;
#pragma unroll
    for (int i = 0; i < 8; ++i) {
        int d = (n0 + i < N) ? __builtin_amdgcn_readlane(cnt8, i) : 0;
        if (d > CAP) d = CAP;
        deg[i] = d;
        degmax = degmax > d ? degmax : d;
    }

    u32 pp[8];
#pragma unroll
    for (int i = 0; i < 8; ++i) {
        int r = n0 + i; if (r >= N) r = N - 1;
        pp[i] = (lane < deg[i]) ? pairs[(size_t)r * CAP + lane] : 0u;
    }

    const int laneoff = lane * 2;
    const char* gbase = (const char*)Gbf;
    float acc[8];
#pragma unroll
    for (int i = 0; i < 8; ++i) acc[i] = 0.f;

    u32 vA[4][8], vB[4][8], vC[4][8];
#define ISSUE(buf, jj)                                                          \
    _Pragma("unroll") for (int s = 0; s < 4; ++s)                               \
    _Pragma("unroll") for (int i = 0; i < 8; ++i) {                             \
        u32 row = ((u32)__builtin_amdgcn_readlane((int)pp[i], (jj) + s)) & 0xFFFFu; \
        buf[s][i] = (u32)*(const u16*)(gbase + ((size_t)row << 7) + laneoff);   \
    }
#define CONSUME(buf, jj)                                                        \
    _Pragma("unroll") for (int s = 0; s < 4; ++s)                               \
    _Pragma("unroll") for (int i = 0; i < 8; ++i) {                             \
        u32 u = (u32)__builtin_amdgcn_readlane((int)pp[i], (jj) + s);           \
        acc[i] = fmaf(__uint_as_float(u & 0xFFFF0000u),                         \
                      __uint_as_float(buf[s][i] << 16), acc[i]);                \
    }

    if (degmax > 0) {
        int j = 0;
        ISSUE(vA, 0)
        if (4 < degmax) ISSUE(vB, 4)
        for (;;) {
            if (j + 8 < degmax) ISSUE(vC, j + 8)
            CONSUME(vA, j)
            j += 4;
            if (j >= degmax) break;
            if (j + 8 < degmax) ISSUE(vA, j + 8)
            CONSUME(vB, j)
            j += 4;
            if (j >= degmax) break;
            if (j + 8 < degmax) ISSUE(vB, j + 8)
            CONSUME(vC, j)
            j += 4;
            if (j >= degmax) break;
        }
    }
#undef ISSUE
#undef CONSUME

#pragma unroll
    for (int i = 0; i < 8; ++i) sw[i * 72 + lane] = f2bf(acc[i]);

    // ---- B fragments: prepacked, 16 x dwordx4 loads ----
    bf16x8 brel[4][2], broot[4][2];
#pragma unroll
    for (int t = 0; t < 4; ++t)
#pragma unroll
        for (int kk = 0; kk < 2; ++kk) {
            brel[t][kk]  = *reinterpret_cast<const bf16x8*>(Wpk + (size_t)(((0 * 4 + t) * 2 + kk) * 64 + lane) * 8);
            broot[t][kk] = *reinterpret_cast<const bf16x8*>(Wpk + (size_t)(((1 * 4 + t) * 2 + kk) * 64 + lane) * 8);
        }

    // ---- A fragments: agg from LDS strip, root from global bf16 ----
    const int am = ml & 7;
    bf16x8 a_agg[2], a_x[2];
#pragma unroll
    for (int kk = 0; kk < 2; ++kk)
        a_agg[kk] = *reinterpret_cast<bf16x8*>(sw + am * 72 + kk * 32 + ql * 8);
    {
        int r = n0 + am; if (r >= N) r = N - 1;
#pragma unroll
        for (int kk = 0; kk < 2; ++kk)
            a_x[kk] = *reinterpret_cast<const bf16x8*>(Gbf + (size_t)r * D + kk * 32 + ql * 8);
    }

    // ---- MFMA + epilogue ----
#pragma unroll
    for (int t = 0; t < 4; ++t) {
        int c = t * 16 + ml;
        float bias = Bpk[c];

        f32x4 accv = {0.f, 0.f, 0.f, 0.f};
        accv = __builtin_amdgcn_mfma_f32_16x16x32_bf16(a_agg[0], brel[t][0],  accv, 0, 0, 0);
        accv = __builtin_amdgcn_mfma_f32_16x16x32_bf16(a_agg[1], brel[t][1],  accv, 0, 0, 0);
        accv = __builtin_amdgcn_mfma_f32_16x16x32_bf16(a_x[0],   broot[t][0], accv, 0, 0, 0);
        accv = __builtin_amdgcn_mfma_f32_16x16x32_bf16(a_x[1],   broot[t][1], accv, 0, 0, 0);
        if (ql < 2) {                       // strip rows 0..7 only
#pragma unroll
            for (int r = 0; r < 4; ++r) {
                int row = n0 + ql * 4 + r;  // C/D: row=(lane>>4)*4+reg, col=lane&15
                if (row < N) {
                    float z = accv[r] + bias;
                    float h = 1.f / (1.f + __expf(-z));
                    int off = row * D + c;
                    if (STAGE == 1) outBf[off] = f2bf(h);
                    else            outF[off]  = h;
                }
            }
        }
    }
}

extern "C" void kernel_launch(void* const* d_in, const int* in_sizes, int n_in,
                              void* d_out, int out_size, void* d_ws, size_t ws_size,
                              hipStream_t stream) {
    const float* X      = (const float*)d_in[0];
    const int*   ei     = (const int*)  d_in[1];
    const float* ew     = (const float*)d_in[2];
    const float* Wrel1  = (const float*)d_in[3];
    const float* brel1  = (const float*)d_in[4];
    const float* Wroot1 = (const float*)d_in[5];
    const float* broot1 = (const float*)d_in[6];
    // d_in[7], d_in[9] (Wrel2, Wroot2) multiply H_prev==0 -> unused
    const float* brel2  = (const float*)d_in[8];
    const float* broot2 = (const float*)d_in[10];
    const float* Wrel3  = (const float*)d_in[11];
    const float* brel3  = (const float*)d_in[12];
    const float* Wroot3 = (const float*)d_in[13];
    const float* broot3 = (const float*)d_in[14];

    const int N = in_sizes[0] / D;
    const int E = in_sizes[1] / 2;

    char* ws = (char*)d_ws;
    int* cnt = (int*)ws;
    size_t off = (((size_t)N * 4) + 255) & ~(size_t)255;
    u32* pairs = (u32*)(ws + off);        off += (size_t)N * CAP * 4;
    u16* Xbf   = (u16*)(ws + off);        off += (size_t)N * D * 2;
    u16* Hbf   = (u16*)(ws + off);        off += (size_t)N * D * 2;
    u16* Wpk   = (u16*)(ws + off);        off += (size_t)32 * 64 * 8 * 2;
    float* Bpk = (float*)(ws + off);

    {
        int n4 = N * D / 4;
        int T  = n4 > N ? n4 : N;
        k_prep<<<(T + 255) / 256, 256, 0, stream>>>(
            X, Xbf, cnt, n4, N, Wrel1, Wroot1, Wrel3, Wroot3,
            brel1, broot1, brel2, broot2, brel3, broot3, Wpk, Bpk);
    }
    {
        int step = (N + 7) / 8;
        k_fill<<<1600, 256, 0, stream>>>(ei, ew, cnt, pairs, E, step);
    }

    const int NB = (N + 31) / 32;
    k_stage<1><<<NB, 256, 0, stream>>>(Xbf, Wpk, Bpk,
                                       cnt, pairs, nullptr, Hbf, N);
    k_stage<2><<<NB, 256, 0, stream>>>(Hbf, Wpk + 16 * 64 * 8, Bpk + 64,
                                       cnt, pairs, (float*)d_out, nullptr, N);
}

// Round 9
// 202.281 us; speedup vs baseline: 1.4267x; 1.0588x over previous
//
#include <hip/hip_runtime.h>

#define D 64
#define CAP 64

typedef unsigned short u16;
typedef unsigned int u32;
typedef short bf16x8 __attribute__((ext_vector_type(8)));
typedef float f32x4 __attribute__((ext_vector_type(4)));

__device__ __forceinline__ u16 f2bf(float f) {
    u32 u = __float_as_uint(f);
    return (u16)((u + 0x7FFFu + ((u >> 16) & 1u)) >> 16);   // RNE
}

// ---- X->bf16 convert + cnt zeroing + W-fragment prepack + bias prepack ----
__global__ void k_prep(const float* __restrict__ X, u16* __restrict__ Xbf,
                       int* __restrict__ cnt, int n4, int N,
                       const float* __restrict__ Wrel1, const float* __restrict__ Wroot1,
                       const float* __restrict__ Wrel3, const float* __restrict__ Wroot3,
                       const float* __restrict__ brel1, const float* __restrict__ broot1,
                       const float* __restrict__ brel2, const float* __restrict__ broot2,
                       const float* __restrict__ brel3, const float* __restrict__ broot3,
                       u16* __restrict__ Wpk, float* __restrict__ Bpk) {
    int i = blockIdx.x * blockDim.x + threadIdx.x;
    if (i < N) cnt[i] = 0;

    if (i < 2048) {           // W fragment prepack: 32 frags x 64 lanes
        int f    = i >> 6;    // ((stage*2+mat)*4+t)*2+kk
        int lane = i & 63;
        int stage = f >> 4, rest = f & 15;
        int mat = rest >> 3, t = (rest >> 1) & 3, kk = rest & 1;
        int ml = lane & 15, ql = lane >> 4;
        const float* W = stage ? (mat ? Wroot3 : Wrel3) : (mat ? Wroot1 : Wrel1);
        const float* src = W + (t * 16 + ml) * D + kk * 32 + ql * 8;
        union { u16 h[8]; uint4 v; } o;
#pragma unroll
        for (int e = 0; e < 8; ++e) o.h[e] = f2bf(src[e]);
        *reinterpret_cast<uint4*>(Wpk + (size_t)(f * 64 + lane) * 8) = o.v;
    }
    if (i < 128) {            // bias prepack
        int stage = i >> 6, c = i & 63;
        Bpk[i] = stage ? (brel3[c] + broot3[c])
                       : (brel1[c] + broot1[c] + brel2[c] + broot2[c]);
    }

    if (i >= n4) return;
    float4 v = reinterpret_cast<const float4*>(X)[i];
    ushort4 o;
    o.x = f2bf(v.x); o.y = f2bf(v.y); o.z = f2bf(v.z); o.w = f2bf(v.w);
    reinterpret_cast<ushort4*>(Xbf)[i] = o;
}

// ---- XCD-partitioned bucket fill (proven R6 version) ----
__global__ void k_fill(const int* __restrict__ ei, const float* __restrict__ ew,
                       int* __restrict__ cnt, u32* __restrict__ pairs,
                       int E, int step) {
    const int g  = blockIdx.x & 7;
    const int b  = blockIdx.x >> 3;
    const int lo = g * step;
    const int hi = lo + step;
    const int nthr = (gridDim.x >> 3) * blockDim.x;
    const int t  = b * blockDim.x + threadIdx.x;
    const int nchunk = E >> 2;

    for (int c = t; c < nchunk; c += nthr) {
        int e = c * 4;
        int4 d4 = *reinterpret_cast<const int4*>(ei + E + e);
#define DO_EDGE(dd, kk)                                                          \
        if ((dd) >= lo && (dd) < hi) {                                           \
            int p = atomicAdd(cnt + (dd), 1);                                    \
            if (p < CAP)                                                         \
                pairs[(dd) * CAP + p] =                                          \
                    (((u32)f2bf(ew[e + kk])) << 16) | (u32)ei[e + kk];           \
        }
        DO_EDGE(d4.x, 0)
        DO_EDGE(d4.y, 1)
        DO_EDGE(d4.z, 2)
        DO_EDGE(d4.w, 3)
#undef DO_EDGE
    }
    if (g == 0 && t == 0) {
        for (int e = nchunk * 4; e < E; ++e) {
            int d = ei[E + e];
            int p = atomicAdd(cnt + d, 1);
            if (p < CAP) pairs[d * CAP + p] = (((u32)f2bf(ew[e])) << 16) | (u32)ei[e];
        }
    }
}

// ---- fused stage: 8-node strip, split-wave paired gather + MFMA + sigmoid ----
// Gather fetches TWO rows per load: lanes 0-31 = node 2p (channels 2*(lane&31),
// +1), lanes 32-63 = node 2p+1. One u32 load serves 2 edge-records; record
// (weight|src) carried in VGPR from issue to consume (no re-readlane).
// launch_bounds (256,3): R7 lesson — tighter caps cause scratch spill.
template <int STAGE>
__global__ __launch_bounds__(256, 3) void k_stage(
        const u16* __restrict__ Gbf,
        const u16* __restrict__ Wpk,   // 16 frags x 64 lanes x 8 bf16 (this stage)
        const float* __restrict__ Bpk, // 64 floats (this stage)
        const int* __restrict__ cnt, const u32* __restrict__ pairs,
        float* __restrict__ outF, u16* __restrict__ outBf, int N) {
    __shared__ __align__(16) u16 smem[4 * 8 * 72];
    const int lane = threadIdx.x & 63;
    const int wid  = threadIdx.x >> 6;
    const int ml   = lane & 15;
    const int ql   = lane >> 4;
    const int half = lane >> 5;    // 0 -> node 2p, 1 -> node 2p+1
    const int hl   = lane & 31;    // channel-pair index (covers ch 2hl, 2hl+1)
    const int n0   = blockIdx.x * 32 + wid * 8;
    u16* sw = smem + wid * 8 * 72;

    if (n0 >= N) return;   // waves independent, no barriers

    int cidx = n0 + (lane & 7); if (cidx >= N) cidx = N - 1;
    const int cnt8 = cnt[cidx];

    int deg[8], degmax = 0;
#pragma unroll
    for (int i = 0; i < 8; ++i) {
        int d = (n0 + i < N) ? __builtin_amdgcn_readlane(cnt8, i) : 0;
        if (d > CAP) d = CAP;
        deg[i] = d;
        degmax = degmax > d ? degmax : d;
    }

    u32 pp[8];
#pragma unroll
    for (int i = 0; i < 8; ++i) {
        int r = n0 + i; if (r >= N) r = N - 1;
        pp[i] = (lane < deg[i]) ? pairs[(size_t)r * CAP + lane] : 0u;
    }

    const u32* grow = reinterpret_cast<const u32*>(Gbf);   // 32 u32 per row
    float2 acc2[4];
#pragma unroll
    for (int p = 0; p < 4; ++p) acc2[p] = make_float2(0.f, 0.f);

    u32 vA[4][4], wA[4][4], vB[4][4], wB[4][4], vC[4][4], wC[4][4];
#define ISSUE(vbuf, wbuf, jj)                                                   \
    _Pragma("unroll") for (int s = 0; s < 4; ++s)                               \
    _Pragma("unroll") for (int p = 0; p < 4; ++p) {                             \
        u32 sa = (u32)__builtin_amdgcn_readlane((int)pp[2 * p],     (jj) + s);  \
        u32 sb = (u32)__builtin_amdgcn_readlane((int)pp[2 * p + 1], (jj) + s);  \
        u32 sel = half ? sb : sa;                                               \
        wbuf[s][p] = sel;                                                       \
        vbuf[s][p] = grow[((sel & 0xFFFFu) << 5) + hl];                         \
    }
#define CONSUME(vbuf, wbuf)                                                     \
    _Pragma("unroll") for (int s = 0; s < 4; ++s)                               \
    _Pragma("unroll") for (int p = 0; p < 4; ++p) {                             \
        float w  = __uint_as_float(wbuf[s][p] & 0xFFFF0000u);                   \
        u32   d  = vbuf[s][p];                                                  \
        acc2[p].x = fmaf(w, __uint_as_float(d << 16),          acc2[p].x);      \
        acc2[p].y = fmaf(w, __uint_as_float(d & 0xFFFF0000u),  acc2[p].y);      \
    }

    if (degmax > 0) {
        int j = 0;
        ISSUE(vA, wA, 0)
        if (4 < degmax) ISSUE(vB, wB, 4)
        for (;;) {
            if (j + 8 < degmax) ISSUE(vC, wC, j + 8)
            CONSUME(vA, wA)
            j += 4;
            if (j >= degmax) break;
            if (j + 8 < degmax) ISSUE(vA, wA, j + 8)
            CONSUME(vB, wB)
            j += 4;
            if (j >= degmax) break;
            if (j + 8 < degmax) ISSUE(vB, wB, j + 8)
            CONSUME(vC, wC)
            j += 4;
            if (j >= degmax) break;
        }
    }
#undef ISSUE
#undef CONSUME

    // acc -> LDS strip: lane holds channels (2hl, 2hl+1) of node 2p+half
#pragma unroll
    for (int p = 0; p < 4; ++p) {
        u32 packed = ((u32)f2bf(acc2[p].y) << 16) | (u32)f2bf(acc2[p].x);
        int row = 2 * p + half;
        *reinterpret_cast<u32*>(sw + row * 72 + hl * 2) = packed;
    }

    // ---- B fragments: prepacked, 16 x dwordx4 loads ----
    bf16x8 brel[4][2], broot[4][2];
#pragma unroll
    for (int t = 0; t < 4; ++t)
#pragma unroll
        for (int kk = 0; kk < 2; ++kk) {
            brel[t][kk]  = *reinterpret_cast<const bf16x8*>(Wpk + (size_t)(((0 * 4 + t) * 2 + kk) * 64 + lane) * 8);
            broot[t][kk] = *reinterpret_cast<const bf16x8*>(Wpk + (size_t)(((1 * 4 + t) * 2 + kk) * 64 + lane) * 8);
        }

    // ---- A fragments: agg from LDS strip, root from global bf16 ----
    const int am = ml & 7;
    bf16x8 a_agg[2], a_x[2];
#pragma unroll
    for (int kk = 0; kk < 2; ++kk)
        a_agg[kk] = *reinterpret_cast<bf16x8*>(sw + am * 72 + kk * 32 + ql * 8);
    {
        int r = n0 + am; if (r >= N) r = N - 1;
#pragma unroll
        for (int kk = 0; kk < 2; ++kk)
            a_x[kk] = *reinterpret_cast<const bf16x8*>(Gbf + (size_t)r * D + kk * 32 + ql * 8);
    }

    // ---- MFMA + epilogue ----
#pragma unroll
    for (int t = 0; t < 4; ++t) {
        int c = t * 16 + ml;
        float bias = Bpk[c];

        f32x4 accv = {0.f, 0.f, 0.f, 0.f};
        accv = __builtin_amdgcn_mfma_f32_16x16x32_bf16(a_agg[0], brel[t][0],  accv, 0, 0, 0);
        accv = __builtin_amdgcn_mfma_f32_16x16x32_bf16(a_agg[1], brel[t][1],  accv, 0, 0, 0);
        accv = __builtin_amdgcn_mfma_f32_16x16x32_bf16(a_x[0],   broot[t][0], accv, 0, 0, 0);
        accv = __builtin_amdgcn_mfma_f32_16x16x32_bf16(a_x[1],   broot[t][1], accv, 0, 0, 0);
        if (ql < 2) {                       // strip rows 0..7 only
#pragma unroll
            for (int r = 0; r < 4; ++r) {
                int row = n0 + ql * 4 + r;  // C/D: row=(lane>>4)*4+reg, col=lane&15
                if (row < N) {
                    float z = accv[r] + bias;
                    float h = 1.f / (1.f + __expf(-z));
                    int off = row * D + c;
                    if (STAGE == 1) outBf[off] = f2bf(h);
                    else            outF[off]  = h;
                }
            }
        }
    }
}

extern "C" void kernel_launch(void* const* d_in, const int* in_sizes, int n_in,
                              void* d_out, int out_size, void* d_ws, size_t ws_size,
                              hipStream_t stream) {
    const float* X      = (const float*)d_in[0];
    const int*   ei     = (const int*)  d_in[1];
    const float* ew     = (const float*)d_in[2];
    const float* Wrel1  = (const float*)d_in[3];
    const float* brel1  = (const float*)d_in[4];
    const float* Wroot1 = (const float*)d_in[5];
    const float* broot1 = (const float*)d_in[6];
    // d_in[7], d_in[9] (Wrel2, Wroot2) multiply H_prev==0 -> unused
    const float* brel2  = (const float*)d_in[8];
    const float* broot2 = (const float*)d_in[10];
    const float* Wrel3  = (const float*)d_in[11];
    const float* brel3  = (const float*)d_in[12];
    const float* Wroot3 = (const float*)d_in[13];
    const float* broot3 = (const float*)d_in[14];

    const int N = in_sizes[0] / D;
    const int E = in_sizes[1] / 2;

    char* ws = (char*)d_ws;
    int* cnt = (int*)ws;
    size_t off = (((size_t)N * 4) + 255) & ~(size_t)255;
    u32* pairs = (u32*)(ws + off);        off += (size_t)N * CAP * 4;
    u16* Xbf   = (u16*)(ws + off);        off += (size_t)N * D * 2;
    u16* Hbf   = (u16*)(ws + off);        off += (size_t)N * D * 2;
    u16* Wpk   = (u16*)(ws + off);        off += (size_t)32 * 64 * 8 * 2;
    float* Bpk = (float*)(ws + off);

    {
        int n4 = N * D / 4;
        int T  = n4 > N ? n4 : N;
        k_prep<<<(T + 255) / 256, 256, 0, stream>>>(
            X, Xbf, cnt, n4, N, Wrel1, Wroot1, Wrel3, Wroot3,
            brel1, broot1, brel2, broot2, brel3, broot3, Wpk, Bpk);
    }
    {
        int step = (N + 7) / 8;
        k_fill<<<1600, 256, 0, stream>>>(ei, ew, cnt, pairs, E, step);
    }

    const int NB = (N + 31) / 32;
    k_stage<1><<<NB, 256, 0, stream>>>(Xbf, Wpk, Bpk,
                                       cnt, pairs, nullptr, Hbf, N);
    k_stage<2><<<NB, 256, 0, stream>>>(Hbf, Wpk + 16 * 64 * 8, Bpk + 64,
                                       cnt, pairs, (float*)d_out, nullptr, N);
}

// Round 10
// 198.518 us; speedup vs baseline: 1.4537x; 1.0190x over previous
//
#include <hip/hip_runtime.h>

#define D 64
#define CAP 64

typedef unsigned short u16;
typedef unsigned int u32;
typedef short bf16x8 __attribute__((ext_vector_type(8)));
typedef float f32x4 __attribute__((ext_vector_type(4)));

__device__ __forceinline__ u16 f2bf(float f) {
    u32 u = __float_as_uint(f);
    return (u16)((u + 0x7FFFu + ((u >> 16) & 1u)) >> 16);   // RNE
}

// ---- X->bf16 convert + cnt zeroing + W-fragment prepack + bias prepack ----
__global__ void k_prep(const float* __restrict__ X, u16* __restrict__ Xbf,
                       int* __restrict__ cnt, int n4, int N,
                       const float* __restrict__ Wrel1, const float* __restrict__ Wroot1,
                       const float* __restrict__ Wrel3, const float* __restrict__ Wroot3,
                       const float* __restrict__ brel1, const float* __restrict__ broot1,
                       const float* __restrict__ brel2, const float* __restrict__ broot2,
                       const float* __restrict__ brel3, const float* __restrict__ broot3,
                       u16* __restrict__ Wpk, float* __restrict__ Bpk) {
    int i = blockIdx.x * blockDim.x + threadIdx.x;
    if (i < N) cnt[i] = 0;

    if (i < 2048) {           // W fragment prepack: 32 frags x 64 lanes
        int f    = i >> 6;    // ((stage*2+mat)*4+t)*2+kk
        int lane = i & 63;
        int stage = f >> 4, rest = f & 15;
        int mat = rest >> 3, t = (rest >> 1) & 3, kk = rest & 1;
        int ml = lane & 15, ql = lane >> 4;
        const float* W = stage ? (mat ? Wroot3 : Wrel3) : (mat ? Wroot1 : Wrel1);
        const float* src = W + (t * 16 + ml) * D + kk * 32 + ql * 8;
        union { u16 h[8]; uint4 v; } o;
#pragma unroll
        for (int e = 0; e < 8; ++e) o.h[e] = f2bf(src[e]);
        *reinterpret_cast<uint4*>(Wpk + (size_t)(f * 64 + lane) * 8) = o.v;
    }
    if (i < 128) {            // bias prepack
        int stage = i >> 6, c = i & 63;
        Bpk[i] = stage ? (brel3[c] + broot3[c])
                       : (brel1[c] + broot1[c] + brel2[c] + broot2[c]);
    }

    if (i >= n4) return;
    float4 v = reinterpret_cast<const float4*>(X)[i];
    ushort4 o;
    o.x = f2bf(v.x); o.y = f2bf(v.y); o.z = f2bf(v.z); o.w = f2bf(v.w);
    reinterpret_cast<ushort4*>(Xbf)[i] = o;
}

// ---- XCD-partitioned bucket fill (proven R6 version) ----
__global__ void k_fill(const int* __restrict__ ei, const float* __restrict__ ew,
                       int* __restrict__ cnt, u32* __restrict__ pairs,
                       int E, int step) {
    const int g  = blockIdx.x & 7;
    const int b  = blockIdx.x >> 3;
    const int lo = g * step;
    const int hi = lo + step;
    const int nthr = (gridDim.x >> 3) * blockDim.x;
    const int t  = b * blockDim.x + threadIdx.x;
    const int nchunk = E >> 2;

    for (int c = t; c < nchunk; c += nthr) {
        int e = c * 4;
        int4 d4 = *reinterpret_cast<const int4*>(ei + E + e);
#define DO_EDGE(dd, kk)                                                          \
        if ((dd) >= lo && (dd) < hi) {                                           \
            int p = atomicAdd(cnt + (dd), 1);                                    \
            if (p < CAP)                                                         \
                pairs[(dd) * CAP + p] =                                          \
                    (((u32)f2bf(ew[e + kk])) << 16) | (u32)ei[e + kk];           \
        }
        DO_EDGE(d4.x, 0)
        DO_EDGE(d4.y, 1)
        DO_EDGE(d4.z, 2)
        DO_EDGE(d4.w, 3)
#undef DO_EDGE
    }
    if (g == 0 && t == 0) {
        for (int e = nchunk * 4; e < E; ++e) {
            int d = ei[E + e];
            int p = atomicAdd(cnt + d, 1);
            if (p < CAP) pairs[d * CAP + p] = (((u32)f2bf(ew[e])) << 16) | (u32)ei[e];
        }
    }
}

// ---- fused stage: 8-node strip, quarter-wave gather + MFMA + sigmoid ----
// Gather fetches FOUR rows per load instruction: quarter q = lane>>4 handles
// node 4p+q; each lane loads uint2 (4 channels). One VMEM inst serves 4
// edge-records. Record carried in VGPR issue->consume (no re-readlane).
// launch_bounds (256,3): R7 lesson — tighter caps cause scratch spill.
template <int STAGE>
__global__ __launch_bounds__(256, 3) void k_stage(
        const u16* __restrict__ Gbf,
        const u16* __restrict__ Wpk,   // 16 frags x 64 lanes x 8 bf16 (this stage)
        const float* __restrict__ Bpk, // 64 floats (this stage)
        const int* __restrict__ cnt, const u32* __restrict__ pairs,
        float* __restrict__ outF, u16* __restrict__ outBf, int N) {
    __shared__ __align__(16) u16 smem[4 * 8 * 72];
    const int lane = threadIdx.x & 63;
    const int wid  = threadIdx.x >> 6;
    const int ml   = lane & 15;
    const int ql   = lane >> 4;     // quarter q: handles node 4p+q in gather
    const int hq   = lane & 15;     // channel-quad: channels 4hq..4hq+3
    const int n0   = blockIdx.x * 32 + wid * 8;
    u16* sw = smem + wid * 8 * 72;

    if (n0 >= N) return;   // waves independent, no barriers

    int cidx = n0 + (lane & 7); if (cidx >= N) cidx = N - 1;
    const int cnt8 = cnt[cidx];

    int deg[8], degmax = 0;
#pragma unroll
    for (int i = 0; i < 8; ++i) {
        int d = (n0 + i < N) ? __builtin_amdgcn_readlane(cnt8, i) : 0;
        if (d > CAP) d = CAP;
        deg[i] = d;
        degmax = degmax > d ? degmax : d;
    }

    u32 pp[8];
#pragma unroll
    for (int i = 0; i < 8; ++i) {
        int r = n0 + i; if (r >= N) r = N - 1;
        pp[i] = (lane < deg[i]) ? pairs[(size_t)r * CAP + lane] : 0u;
    }

    const bool qb0 = (ql & 1) != 0;
    const bool qb1 = (ql & 2) != 0;
    const int  hq8 = hq * 8;                 // byte offset of lane's 4 channels
    const char* gbase = (const char*)Gbf;    // 128 B per row

    f32x4 acc[2];
#pragma unroll
    for (int p = 0; p < 2; ++p) acc[p] = (f32x4){0.f, 0.f, 0.f, 0.f};

    uint2 vA[4][2], vB[4][2], vC[4][2];
    u32   wA[4][2], wB[4][2], wC[4][2];
#define ISSUE(vbuf, wbuf, jj)                                                   \
    _Pragma("unroll") for (int s = 0; s < 4; ++s)                               \
    _Pragma("unroll") for (int p = 0; p < 2; ++p) {                             \
        u32 r0 = (u32)__builtin_amdgcn_readlane((int)pp[4 * p + 0], (jj) + s);  \
        u32 r1 = (u32)__builtin_amdgcn_readlane((int)pp[4 * p + 1], (jj) + s);  \
        u32 r2 = (u32)__builtin_amdgcn_readlane((int)pp[4 * p + 2], (jj) + s);  \
        u32 r3 = (u32)__builtin_amdgcn_readlane((int)pp[4 * p + 3], (jj) + s);  \
        u32 c01 = qb0 ? r1 : r0;                                                \
        u32 c23 = qb0 ? r3 : r2;                                                \
        u32 sel = qb1 ? c23 : c01;                                              \
        wbuf[s][p] = sel;                                                       \
        vbuf[s][p] = *(const uint2*)(gbase + ((size_t)(sel & 0xFFFFu) << 7) + hq8); \
    }
#define CONSUME(vbuf, wbuf)                                                     \
    _Pragma("unroll") for (int s = 0; s < 4; ++s)                               \
    _Pragma("unroll") for (int p = 0; p < 2; ++p) {                             \
        float w  = __uint_as_float(wbuf[s][p] & 0xFFFF0000u);                   \
        uint2 d  = vbuf[s][p];                                                  \
        acc[p][0] = fmaf(w, __uint_as_float(d.x << 16),         acc[p][0]);     \
        acc[p][1] = fmaf(w, __uint_as_float(d.x & 0xFFFF0000u), acc[p][1]);     \
        acc[p][2] = fmaf(w, __uint_as_float(d.y << 16),         acc[p][2]);     \
        acc[p][3] = fmaf(w, __uint_as_float(d.y & 0xFFFF0000u), acc[p][3]);     \
    }

    if (degmax > 0) {
        int j = 0;
        ISSUE(vA, wA, 0)
        if (4 < degmax) ISSUE(vB, wB, 4)
        for (;;) {
            if (j + 8 < degmax) ISSUE(vC, wC, j + 8)
            CONSUME(vA, wA)
            j += 4;
            if (j >= degmax) break;
            if (j + 8 < degmax) ISSUE(vA, wA, j + 8)
            CONSUME(vB, wB)
            j += 4;
            if (j >= degmax) break;
            if (j + 8 < degmax) ISSUE(vB, wB, j + 8)
            CONSUME(vC, wC)
            j += 4;
            if (j >= degmax) break;
        }
    }
#undef ISSUE
#undef CONSUME

    // acc -> LDS strip: lane holds channels 4hq..4hq+3 of node 4p+ql
#pragma unroll
    for (int p = 0; p < 2; ++p) {
        uint2 packed;
        packed.x = ((u32)f2bf(acc[p][1]) << 16) | (u32)f2bf(acc[p][0]);
        packed.y = ((u32)f2bf(acc[p][3]) << 16) | (u32)f2bf(acc[p][2]);
        int row = 4 * p + ql;
        *reinterpret_cast<uint2*>(sw + row * 72 + hq * 4) = packed;  // 144B stride: 8B-aligned
    }

    // ---- B fragments: prepacked, 16 x dwordx4 loads ----
    bf16x8 brel[4][2], broot[4][2];
#pragma unroll
    for (int t = 0; t < 4; ++t)
#pragma unroll
        for (int kk = 0; kk < 2; ++kk) {
            brel[t][kk]  = *reinterpret_cast<const bf16x8*>(Wpk + (size_t)(((0 * 4 + t) * 2 + kk) * 64 + lane) * 8);
            broot[t][kk] = *reinterpret_cast<const bf16x8*>(Wpk + (size_t)(((1 * 4 + t) * 2 + kk) * 64 + lane) * 8);
        }

    // ---- A fragments: agg from LDS strip, root from global bf16 ----
    const int am = ml & 7;
    bf16x8 a_agg[2], a_x[2];
#pragma unroll
    for (int kk = 0; kk < 2; ++kk)
        a_agg[kk] = *reinterpret_cast<bf16x8*>(sw + am * 72 + kk * 32 + ql * 8);
    {
        int r = n0 + am; if (r >= N) r = N - 1;
#pragma unroll
        for (int kk = 0; kk < 2; ++kk)
            a_x[kk] = *reinterpret_cast<const bf16x8*>(Gbf + (size_t)r * D + kk * 32 + ql * 8);
    }

    // ---- MFMA + epilogue ----
#pragma unroll
    for (int t = 0; t < 4; ++t) {
        int c = t * 16 + ml;
        float bias = Bpk[c];

        f32x4 accv = {0.f, 0.f, 0.f, 0.f};
        accv = __builtin_amdgcn_mfma_f32_16x16x32_bf16(a_agg[0], brel[t][0],  accv, 0, 0, 0);
        accv = __builtin_amdgcn_mfma_f32_16x16x32_bf16(a_agg[1], brel[t][1],  accv, 0, 0, 0);
        accv = __builtin_amdgcn_mfma_f32_16x16x32_bf16(a_x[0],   broot[t][0], accv, 0, 0, 0);
        accv = __builtin_amdgcn_mfma_f32_16x16x32_bf16(a_x[1],   broot[t][1], accv, 0, 0, 0);
        if (ql < 2) {                       // strip rows 0..7 only
#pragma unroll
            for (int r = 0; r < 4; ++r) {
                int row = n0 + ql * 4 + r;  // C/D: row=(lane>>4)*4+reg, col=lane&15
                if (row < N) {
                    float z = accv[r] + bias;
                    float h = 1.f / (1.f + __expf(-z));
                    int off = row * D + c;
                    if (STAGE == 1) outBf[off] = f2bf(h);
                    else            outF[off]  = h;
                }
            }
        }
    }
}

extern "C" void kernel_launch(void* const* d_in, const int* in_sizes, int n_in,
                              void* d_out, int out_size, void* d_ws, size_t ws_size,
                              hipStream_t stream) {
    const float* X      = (const float*)d_in[0];
    const int*   ei     = (const int*)  d_in[1];
    const float* ew     = (const float*)d_in[2];
    const float* Wrel1  = (const float*)d_in[3];
    const float* brel1  = (const float*)d_in[4];
    const float* Wroot1 = (const float*)d_in[5];
    const float* broot1 = (const float*)d_in[6];
    // d_in[7], d_in[9] (Wrel2, Wroot2) multiply H_prev==0 -> unused
    const float* brel2  = (const float*)d_in[8];
    const float* broot2 = (const float*)d_in[10];
    const float* Wrel3  = (const float*)d_in[11];
    const float* brel3  = (const float*)d_in[12];
    const float* Wroot3 = (const float*)d_in[13];
    const float* broot3 = (const float*)d_in[14];

    const int N = in_sizes[0] / D;
    const int E = in_sizes[1] / 2;

    char* ws = (char*)d_ws;
    int* cnt = (int*)ws;
    size_t off = (((size_t)N * 4) + 255) & ~(size_t)255;
    u32* pairs = (u32*)(ws + off);        off += (size_t)N * CAP * 4;
    u16* Xbf   = (u16*)(ws + off);        off += (size_t)N * D * 2;
    u16* Hbf   = (u16*)(ws + off);        off += (size_t)N * D * 2;
    u16* Wpk   = (u16*)(ws + off);        off += (size_t)32 * 64 * 8 * 2;
    float* Bpk = (float*)(ws + off);

    {
        int n4 = N * D / 4;
        int T  = n4 > N ? n4 : N;
        k_prep<<<(T + 255) / 256, 256, 0, stream>>>(
            X, Xbf, cnt, n4, N, Wrel1, Wroot1, Wrel3, Wroot3,
            brel1, broot1, brel2, broot2, brel3, broot3, Wpk, Bpk);
    }
    {
        int step = (N + 7) / 8;
        k_fill<<<1600, 256, 0, stream>>>(ei, ew, cnt, pairs, E, step);
    }

    const int NB = (N + 31) / 32;
    k_stage<1><<<NB, 256, 0, stream>>>(Xbf, Wpk, Bpk,
                                       cnt, pairs, nullptr, Hbf, N);
    k_stage<2><<<NB, 256, 0, stream>>>(Hbf, Wpk + 16 * 64 * 8, Bpk + 64,
                                       cnt, pairs, (float*)d_out, nullptr, N);
}